// Round 2
// baseline (1154.641 us; speedup 1.0000x reference)
//
#include <hip/hip_runtime.h>
#include <stdint.h>

// ---------------------------------------------------------------------------
// Problem constants: B=4, T=1024, C=1024, H=16, hs=64
// qkv GEMM: [4096,1024] @ [1024->3072]^T ; attn per (b,h) ; proj [4096,1024]@[1024,1024]^T
//
// Key insight: att + stop_grad(bernoulli(att) - att) == the Bernoulli samples
// exactly in fp32, so y = samples @ V, att_sum = popcount, att_var == 0.
// Samples must reproduce JAX threefry2x32 bit-exactly. Modern JAX uses the
// PARTITIONABLE stream: bits[i] = b1 ^ b2 where (b1,b2) = threefry(key,(0,i)).
// ---------------------------------------------------------------------------

#define T_SEQ 1024
#define QKV_LD 3072
#define HS 64

__device__ __forceinline__ uint32_t rotl32(uint32_t x, int d) {
  return (x << d) | (x >> (32 - d));
}

// Exact JAX threefry2x32 (20 rounds).
__device__ __forceinline__ void threefry2x32(uint32_t k0, uint32_t k1,
                                             uint32_t x0, uint32_t x1,
                                             uint32_t &o0, uint32_t &o1) {
  uint32_t ks2 = k0 ^ k1 ^ 0x1BD11BDAu;
#define TF_R4(a, b, c, d)                                                      \
  x0 += x1; x1 = rotl32(x1, a); x1 ^= x0;                                      \
  x0 += x1; x1 = rotl32(x1, b); x1 ^= x0;                                      \
  x0 += x1; x1 = rotl32(x1, c); x1 ^= x0;                                      \
  x0 += x1; x1 = rotl32(x1, d); x1 ^= x0;
  x0 += k0; x1 += k1;
  TF_R4(13, 15, 26, 6)
  x0 += k1; x1 += ks2 + 1u;
  TF_R4(17, 29, 16, 24)
  x0 += ks2; x1 += k0 + 2u;
  TF_R4(13, 15, 26, 6)
  x0 += k0; x1 += k1 + 3u;
  TF_R4(17, 29, 16, 24)
  x0 += k1; x1 += ks2 + 4u;
  TF_R4(13, 15, 26, 6)
  x0 += ks2; x1 += k0 + 5u;
  o0 = x0; o1 = x1;
#undef TF_R4
}

// ---------------------------------------------------------------------------
// fp32 GEMM: C[M,N] = A[M,K] @ B[N,K]^T  (both operands K-contiguous)
// 128x128 tile, BK=32, 256 threads, 8x8 micro-tile with 64-split columns/rows.
// LDS stored transposed [kk][m] with row stride 132 (bank-spread).
// ---------------------------------------------------------------------------
#define GBK 32
#define GLDS 132

__global__ __launch_bounds__(256) void gemm_nt(const float* __restrict__ A,
                                               const float* __restrict__ B,
                                               float* __restrict__ C,
                                               int M, int N, int K) {
  __shared__ float As[GBK][GLDS];
  __shared__ float Bs[GBK][GLDS];
  const int t = threadIdx.x;
  const int tx = t & 15, ty = t >> 4;
  const int bm = blockIdx.x * 128;
  const int bn = blockIdx.y * 128;

  float acc[8][8];
#pragma unroll
  for (int i = 0; i < 8; ++i)
#pragma unroll
    for (int j = 0; j < 8; ++j) acc[i][j] = 0.f;

  for (int k0 = 0; k0 < K; k0 += GBK) {
    __syncthreads();
    // stage A,B tiles (128 rows x 32 k), transposed into LDS
#pragma unroll
    for (int it = 0; it < 4; ++it) {
      int q = it * 256 + t;
      int row = q >> 3, cq = q & 7;
      float4 av = *reinterpret_cast<const float4*>(&A[(size_t)(bm + row) * K + k0 + cq * 4]);
      float4 bv = *reinterpret_cast<const float4*>(&B[(size_t)(bn + row) * K + k0 + cq * 4]);
      int kk = cq * 4;
      As[kk + 0][row] = av.x; As[kk + 1][row] = av.y;
      As[kk + 2][row] = av.z; As[kk + 3][row] = av.w;
      Bs[kk + 0][row] = bv.x; Bs[kk + 1][row] = bv.y;
      Bs[kk + 2][row] = bv.z; Bs[kk + 3][row] = bv.w;
    }
    __syncthreads();
#pragma unroll
    for (int kk = 0; kk < GBK; ++kk) {
      float4 al = *reinterpret_cast<const float4*>(&As[kk][4 * ty]);
      float4 ah = *reinterpret_cast<const float4*>(&As[kk][64 + 4 * ty]);
      float4 bl = *reinterpret_cast<const float4*>(&Bs[kk][4 * tx]);
      float4 bh = *reinterpret_cast<const float4*>(&Bs[kk][64 + 4 * tx]);
      float a[8] = {al.x, al.y, al.z, al.w, ah.x, ah.y, ah.z, ah.w};
      float b[8] = {bl.x, bl.y, bl.z, bl.w, bh.x, bh.y, bh.z, bh.w};
#pragma unroll
      for (int i = 0; i < 8; ++i)
#pragma unroll
        for (int j = 0; j < 8; ++j) acc[i][j] = fmaf(a[i], b[j], acc[i][j]);
    }
  }
#pragma unroll
  for (int i = 0; i < 8; ++i) {
    int r = bm + ((i < 4) ? (4 * ty + i) : (64 + 4 * ty + (i - 4)));
    float4 lo = make_float4(acc[i][0], acc[i][1], acc[i][2], acc[i][3]);
    float4 hi = make_float4(acc[i][4], acc[i][5], acc[i][6], acc[i][7]);
    *reinterpret_cast<float4*>(&C[(size_t)r * N + bn + 4 * tx]) = lo;
    *reinterpret_cast<float4*>(&C[(size_t)r * N + bn + 64 + 4 * tx]) = hi;
  }
}

// ---------------------------------------------------------------------------
// Fused sigmoid attention + exact JAX Bernoulli sampling (partitionable
// threefry: bits[i] = o0 ^ o1 of threefry(key, (0, i)), i = 26-bit flat idx).
// One block per (bh, q-tile of 64). 256 threads, 4x4 micro-tiles.
// LDS tiles [64][64] fp32, quad-XOR swizzle -> conflict-free b128 reads.
// ---------------------------------------------------------------------------
__global__ __launch_bounds__(256) void attn_fused(const float* __restrict__ qkv,
                                                  float* __restrict__ yatt,
                                                  float* __restrict__ att_sum) {
  __shared__ float Qs[64][64];
  __shared__ float Ks[64][64];
  __shared__ float Vs[64][64];
  __shared__ float St[64][64];  // samples, transposed [k][q]

  const int t = threadIdx.x;
  const int tx = t & 15, ty = t >> 4;
  const int bh = blockIdx.x;            // 0..63  (= b*16 + h)
  const int b = bh >> 4, h = bh & 15;
  const int qt = 15 - (int)blockIdx.y;  // heaviest q-tiles dispatched first

  // samp_key = fold_in(key(0), 42) = threefry((0,0),(0,42))  (concat path)
  uint32_t dk0, dk1;
  threefry2x32(0u, 0u, 0u, 42u, dk0, dk1);

  // stage Q tile (64 q-rows x 64 d)
  const float* qbase = qkv + (size_t)(b * T_SEQ + qt * 64) * QKV_LD + h * HS;
#pragma unroll
  for (int it = 0; it < 4; ++it) {
    int q = it * 256 + t;
    int row = q >> 4, cq = q & 15;
    float4 v = *reinterpret_cast<const float4*>(&qbase[(size_t)row * QKV_LD + cq * 4]);
    int pc = cq ^ ((row >> 2) & 7);
    *reinterpret_cast<float4*>(&Qs[row][pc * 4]) = v;
  }

  float yacc[4][4];
#pragma unroll
  for (int i = 0; i < 4; ++i)
#pragma unroll
    for (int j = 0; j < 4; ++j) yacc[i][j] = 0.f;
  float rowsum[4] = {0.f, 0.f, 0.f, 0.f};

  const uint32_t bh_u = (uint32_t)bh;

  for (int kt = 0; kt <= qt; ++kt) {
    __syncthreads();
    // stage K,V tiles
    const float* kb = qkv + (size_t)(b * T_SEQ + kt * 64) * QKV_LD + 1024 + h * HS;
    const float* vb = kb + 1024;
#pragma unroll
    for (int it = 0; it < 4; ++it) {
      int q = it * 256 + t;
      int row = q >> 4, cq = q & 15;
      int pc = cq ^ ((row >> 2) & 7);
      *reinterpret_cast<float4*>(&Ks[row][pc * 4]) =
          *reinterpret_cast<const float4*>(&kb[(size_t)row * QKV_LD + cq * 4]);
      *reinterpret_cast<float4*>(&Vs[row][pc * 4]) =
          *reinterpret_cast<const float4*>(&vb[(size_t)row * QKV_LD + cq * 4]);
    }
    __syncthreads();

    // S = Q . K^T  (fp32, 16 d-quad steps)
    float s[4][4];
#pragma unroll
    for (int i = 0; i < 4; ++i)
#pragma unroll
      for (int j = 0; j < 4; ++j) s[i][j] = 0.f;
#pragma unroll
    for (int c = 0; c < 16; ++c) {
      float aq[4][4], bk[4][4];
#pragma unroll
      for (int i = 0; i < 4; ++i) {
        int r = 4 * ty + i;
        float4 v = *reinterpret_cast<const float4*>(&Qs[r][(c ^ ((r >> 2) & 7)) * 4]);
        aq[i][0] = v.x; aq[i][1] = v.y; aq[i][2] = v.z; aq[i][3] = v.w;
      }
#pragma unroll
      for (int j = 0; j < 4; ++j) {
        int r = 4 * tx + j;
        float4 v = *reinterpret_cast<const float4*>(&Ks[r][(c ^ ((r >> 2) & 7)) * 4]);
        bk[j][0] = v.x; bk[j][1] = v.y; bk[j][2] = v.z; bk[j][3] = v.w;
      }
#pragma unroll
      for (int i = 0; i < 4; ++i)
#pragma unroll
        for (int j = 0; j < 4; ++j)
#pragma unroll
          for (int d = 0; d < 4; ++d) s[i][j] = fmaf(aq[i][d], bk[j][d], s[i][j]);
    }

    // sigmoid + exact threefry Bernoulli sample (partitionable stream)
    float stf[4][4];
    const int qg0 = qt * 64 + 4 * ty;
    const int kg0 = kt * 64 + 4 * tx;
#pragma unroll
    for (int i = 0; i < 4; ++i) {
#pragma unroll
      for (int j = 0; j < 4; ++j) {
        int qg = qg0 + i, kg = kg0 + j;
        float samp = 0.f;
        if (kg <= qg) {
          float e = __expf(-0.125f * s[i][j]);  // p = 1/(1+e)
          uint32_t idx = (bh_u << 20) | ((uint32_t)qg << 10) | (uint32_t)kg;
          uint32_t r0, r1;
          threefry2x32(dk0, dk1, 0u, idx, r0, r1);
          uint32_t bits = r0 ^ r1;
          float u = __uint_as_float(0x3F800000u | (bits >> 9)) - 1.0f;
          // u < 1/(1+e)  <=>  u*(1+e) < 1  (boundary shift ~1 ulp, negligible)
          samp = (u * (1.0f + e) < 1.0f) ? 1.0f : 0.0f;
        }
        stf[i][j] = samp;
        rowsum[i] += samp;
      }
    }
    // write samples transposed St[k][q]
#pragma unroll
    for (int j = 0; j < 4; ++j) {
      int r = 4 * tx + j;
      int pc = ty ^ ((r >> 2) & 7);
      *reinterpret_cast<float4*>(&St[r][pc * 4]) =
          make_float4(stf[0][j], stf[1][j], stf[2][j], stf[3][j]);
    }
    __syncthreads();

    // Y += S @ V
#pragma unroll 8
    for (int k = 0; k < 64; ++k) {
      int g = (k >> 2) & 7;
      float4 sv4 = *reinterpret_cast<const float4*>(&St[k][(ty ^ g) * 4]);
      float4 vv4 = *reinterpret_cast<const float4*>(&Vs[k][(tx ^ g) * 4]);
      float sv[4] = {sv4.x, sv4.y, sv4.z, sv4.w};
      float vv[4] = {vv4.x, vv4.y, vv4.z, vv4.w};
#pragma unroll
      for (int i = 0; i < 4; ++i)
#pragma unroll
        for (int j = 0; j < 4; ++j) yacc[i][j] = fmaf(sv[i], vv[j], yacc[i][j]);
    }
  }

  // write y_att[b, q, h*64 + d]
  const int orow0 = b * T_SEQ + qt * 64 + 4 * ty;
#pragma unroll
  for (int i = 0; i < 4; ++i) {
    *reinterpret_cast<float4*>(&yatt[(size_t)(orow0 + i) * 1024 + h * HS + 4 * tx]) =
        make_float4(yacc[i][0], yacc[i][1], yacc[i][2], yacc[i][3]);
  }
  // att_sum: reduce across the 16 tx lanes (contiguous within a wave)
#pragma unroll
  for (int i = 0; i < 4; ++i) {
    rowsum[i] += __shfl_xor(rowsum[i], 1, 16);
    rowsum[i] += __shfl_xor(rowsum[i], 2, 16);
    rowsum[i] += __shfl_xor(rowsum[i], 4, 16);
    rowsum[i] += __shfl_xor(rowsum[i], 8, 16);
  }
  if (tx == 0) {
#pragma unroll
    for (int i = 0; i < 4; ++i)
      att_sum[(size_t)bh * T_SEQ + qt * 64 + 4 * ty + i] = rowsum[i];
  }
}

// att_var is exactly zero (samples are 0/1, s*(1-s)=0)
__global__ void zero_f4(float4* __restrict__ p) {
  p[(size_t)blockIdx.x * 256 + threadIdx.x] = make_float4(0.f, 0.f, 0.f, 0.f);
}

extern "C" void kernel_launch(void* const* d_in, const int* in_sizes, int n_in,
                              void* d_out, int out_size, void* d_ws, size_t ws_size,
                              hipStream_t stream) {
  (void)in_sizes; (void)n_in; (void)out_size; (void)ws_size;
  const float* x      = (const float*)d_in[0];  // [4,1024,1024]
  const float* w_attn = (const float*)d_in[1];  // [3072,1024]
  const float* w_proj = (const float*)d_in[2];  // [1024,1024]

  float* y_out      = (float*)d_out;                 // [4,1024,1024]
  float* attsum_out = y_out + (size_t)4 * 1024 * 1024;  // [4,16,1024]
  float* attvar_out = attsum_out + (size_t)4 * 16 * 1024;

  float* qkv  = (float*)d_ws;                         // [4096,3072] fp32 = 48 MiB
  float* yatt = qkv + (size_t)4096 * 3072;            // [4096,1024] fp32 = 16 MiB

  dim3 blk(256);
  // qkv = x @ w_attn^T
  gemm_nt<<<dim3(4096 / 128, 3072 / 128), blk, 0, stream>>>(x, w_attn, qkv, 4096, 3072, 1024);
  // fused sigmoid attention + Bernoulli ST sampling
  attn_fused<<<dim3(64, 16), blk, 0, stream>>>(qkv, yatt, attsum_out);
  // y = yatt @ w_proj^T
  gemm_nt<<<dim3(4096 / 128, 1024 / 128), blk, 0, stream>>>(yatt, w_proj, y_out, 4096, 1024, 1024);
  // att_var == 0 exactly
  zero_f4<<<dim3(64), blk, 0, stream>>>((float4*)attvar_out);
}

// Round 3
// 169.306 us; speedup vs baseline: 6.8199x; 6.8199x over previous
//
#include <hip/hip_runtime.h>
#include <stdint.h>

// ---------------------------------------------------------------------------
// B=4, T=1024, C=1024, H=16, hs=64.
// y = samples @ V (straight-through => forward output IS the Bernoulli sample),
// att_sum = per-row sample count, att_var == 0 exactly.
// Pipeline: cvt(x,w)->bf16 ; qkv GEMM (bf16 MFMA) ; fused MFMA attention with
// exact partitionable-threefry sampling ; proj GEMM (bf16 MFMA, f32 out).
// ---------------------------------------------------------------------------

#define T_SEQ 1024
#define QKV_LD 3072

typedef __attribute__((ext_vector_type(8))) short bf16x8;
typedef __attribute__((ext_vector_type(4))) float f32x4;
typedef __attribute__((ext_vector_type(4))) unsigned int u32x4;

#define ROTL(x, d) __builtin_amdgcn_alignbit((x), (x), 32 - (d))

__device__ __forceinline__ void threefry2x32(uint32_t k0, uint32_t k1,
                                             uint32_t x0, uint32_t x1,
                                             uint32_t &o0, uint32_t &o1) {
  uint32_t ks2 = k0 ^ k1 ^ 0x1BD11BDAu;
#define TF_R4(a, b, c, d)                                                      \
  x0 += x1; x1 = ROTL(x1, a); x1 ^= x0;                                        \
  x0 += x1; x1 = ROTL(x1, b); x1 ^= x0;                                        \
  x0 += x1; x1 = ROTL(x1, c); x1 ^= x0;                                        \
  x0 += x1; x1 = ROTL(x1, d); x1 ^= x0;
  x0 += k0; x1 += k1;
  TF_R4(13, 15, 26, 6)
  x0 += k1; x1 += ks2 + 1u;
  TF_R4(17, 29, 16, 24)
  x0 += ks2; x1 += k0 + 2u;
  TF_R4(13, 15, 26, 6)
  x0 += k0; x1 += k1 + 3u;
  TF_R4(17, 29, 16, 24)
  x0 += k1; x1 += ks2 + 4u;
  TF_R4(13, 15, 26, 6)
  x0 += ks2; x1 += k0 + 5u;
  o0 = x0; o1 = x1;
#undef TF_R4
}

__device__ __forceinline__ unsigned short f2bf(float f) {  // RNE
  uint32_t u = __float_as_uint(f);
  u += 0x7FFFu + ((u >> 16) & 1u);
  return (unsigned short)(u >> 16);
}

// f32 -> bf16 bulk convert (4 elems/thread)
__global__ __launch_bounds__(256) void cvt_bf16(const float4* __restrict__ in,
                                                uint2* __restrict__ out) {
  int i = blockIdx.x * 256 + threadIdx.x;
  float4 v = in[i];
  uint2 o;
  o.x = (uint32_t)f2bf(v.x) | ((uint32_t)f2bf(v.y) << 16);
  o.y = (uint32_t)f2bf(v.z) | ((uint32_t)f2bf(v.w) << 16);
  out[i] = o;
}

// ---------------------------------------------------------------------------
// bf16 MFMA GEMM: C[M,N] = A[M,K] @ B[N,K]^T. 128x128 tile, BK=32, 4 waves.
// Reg-staged LDS with XOR swizzle (2-way max on reads). Prefetch next K-tile.
// ---------------------------------------------------------------------------
template <int OUT_BF16>
__global__ __launch_bounds__(256) void gemm_bf16(const unsigned short* __restrict__ A,
                                                 const unsigned short* __restrict__ B,
                                                 void* __restrict__ Cout,
                                                 int M, int N, int K) {
  __shared__ uint32_t As4[128 * 16];  // 128 rows x 32 bf16 (16 words), swizzled
  __shared__ uint32_t Bs4[128 * 16];

  const int t = threadIdx.x;
  const int lane = t & 63, w = t >> 6;
  const int g = lane >> 4, lr = lane & 15;
  const int rw = w >> 1, cw = w & 1;
  const int bm = blockIdx.x * 128, bn = blockIdx.y * 128;

  // staging: thread t covers row sr, 16 bf16 at col 16*sp
  const int sr = t >> 1, sp = t & 1;
  const unsigned short* Asrc = A + (size_t)(bm + sr) * K + 16 * sp;
  const unsigned short* Bsrc = B + (size_t)(bn + sr) * K + 16 * sp;
  const int swz = (sr & 3) << 2;
  const int w0 = (8 * sp) ^ swz;
  const int w1 = (8 * sp + 4) ^ swz;

  f32x4 acc[4][4];
#pragma unroll
  for (int i = 0; i < 4; ++i)
#pragma unroll
    for (int j = 0; j < 4; ++j) acc[i][j] = (f32x4){0.f, 0.f, 0.f, 0.f};

  const int wcA = (4 * g) ^ ((lr & 3) << 2);

  u32x4 a0 = *(const u32x4*)(Asrc);
  u32x4 a1 = *(const u32x4*)(Asrc + 8);
  u32x4 b0 = *(const u32x4*)(Bsrc);
  u32x4 b1 = *(const u32x4*)(Bsrc + 8);

  for (int k0 = 0; k0 < K; k0 += 32) {
    __syncthreads();
    *(u32x4*)&As4[sr * 16 + w0] = a0;
    *(u32x4*)&As4[sr * 16 + w1] = a1;
    *(u32x4*)&Bs4[sr * 16 + w0] = b0;
    *(u32x4*)&Bs4[sr * 16 + w1] = b1;
    __syncthreads();

    const int kn = (k0 + 32 < K) ? k0 + 32 : 0;  // prefetch (dummy on last)
    a0 = *(const u32x4*)(Asrc + kn);
    a1 = *(const u32x4*)(Asrc + kn + 8);
    b0 = *(const u32x4*)(Bsrc + kn);
    b1 = *(const u32x4*)(Bsrc + kn + 8);

    bf16x8 af[4], bfr[4];
#pragma unroll
    for (int i = 0; i < 4; ++i)
      af[i] = *(const bf16x8*)&As4[(64 * rw + 16 * i + lr) * 16 + wcA];
#pragma unroll
    for (int j = 0; j < 4; ++j)
      bfr[j] = *(const bf16x8*)&Bs4[(64 * cw + 16 * j + lr) * 16 + wcA];
#pragma unroll
    for (int i = 0; i < 4; ++i)
#pragma unroll
      for (int j = 0; j < 4; ++j)
        acc[i][j] = __builtin_amdgcn_mfma_f32_16x16x32_bf16(af[i], bfr[j], acc[i][j], 0, 0, 0);
  }

#pragma unroll
  for (int i = 0; i < 4; ++i)
#pragma unroll
    for (int j = 0; j < 4; ++j)
#pragma unroll
      for (int r = 0; r < 4; ++r) {
        const size_t row = bm + 64 * rw + 16 * i + 4 * g + r;
        const size_t col = bn + 64 * cw + 16 * j + lr;
        if (OUT_BF16)
          ((unsigned short*)Cout)[row * N + col] = f2bf(acc[i][j][r]);
        else
          ((float*)Cout)[row * N + col] = acc[i][j][r];
      }
}

// ---------------------------------------------------------------------------
// Fused MFMA attention + exact JAX partitionable-threefry Bernoulli sampling.
// Block = (bh, q-tile 64). 4 waves; wave w owns q rows [16w,16w+16).
// Qs/Ks: [64 rows][64 bf16] XOR-swizzled; Vt: transposed [64 d][64 k] bf16;
// St: per-wave-private [64][68] f32 sample buffer (layout-safe P round-trip).
// ---------------------------------------------------------------------------
__global__ __launch_bounds__(256) void attn_mfma(const unsigned short* __restrict__ qkv,
                                                 unsigned short* __restrict__ yatt,
                                                 float* __restrict__ att_sum) {
  __shared__ uint32_t Qs4[64 * 32];
  __shared__ uint32_t Ks4[64 * 32];
  __shared__ uint32_t Vt4[64 * 32];
  __shared__ float St[64 * 68];

  const int t = threadIdx.x;
  const int lane = t & 63, w = t >> 6;
  const int g = lane >> 4, lr = lane & 15;
  const int bh = blockIdx.x;
  const int b = bh >> 4, h = bh & 15;
  const int qt = 15 - (int)blockIdx.y;  // heavy tiles first
  const int qt64 = qt * 64;

  uint32_t dk0, dk1;  // fold_in(key(0), 42)
  threefry2x32(0u, 0u, 0u, 42u, dk0, dk1);

  // ---- stage Q tile ----
  const unsigned short* qbase = qkv + (size_t)(b * T_SEQ + qt64) * QKV_LD + h * 64;
  {
    const int r = t >> 2, s4 = t & 3;
    const unsigned short* src = qbase + (size_t)r * QKV_LD + 8 * s4;
    u32x4 v0 = *(const u32x4*)(src);
    u32x4 v1 = *(const u32x4*)(src + 32);
    const int sw = (r & 7) << 2;
    *(u32x4*)&Qs4[r * 32 + ((4 * s4) ^ sw)] = v0;
    *(u32x4*)&Qs4[r * 32 + ((4 * s4 + 16) ^ sw)] = v1;
  }
  __syncthreads();

  const int swzr = (lr & 7) << 2;
  bf16x8 aq0, aq1;  // Q A-frags, constant across k-tiles
  {
    const uint32_t* qrow = &Qs4[(16 * w + lr) * 32];
    aq0 = *(const bf16x8*)&qrow[(4 * g) ^ swzr];
    aq1 = *(const bf16x8*)&qrow[(4 * g + 16) ^ swzr];
  }

  f32x4 yacc[4];
#pragma unroll
  for (int c = 0; c < 4; ++c) yacc[c] = (f32x4){0.f, 0.f, 0.f, 0.f};
  float rs[4] = {0.f, 0.f, 0.f, 0.f};

  for (int kt = 0; kt <= qt; ++kt) {
    __syncthreads();  // prev tile's Ks/Vt reads done
    // ---- stage K tile ----
    const unsigned short* kb = qkv + (size_t)(b * T_SEQ + kt * 64) * QKV_LD + 1024 + h * 64;
    {
      const int r = t >> 2, s4 = t & 3;
      const unsigned short* src = kb + (size_t)r * QKV_LD + 8 * s4;
      u32x4 v0 = *(const u32x4*)(src);
      u32x4 v1 = *(const u32x4*)(src + 32);
      const int sw = (r & 7) << 2;
      *(u32x4*)&Ks4[r * 32 + ((4 * s4) ^ sw)] = v0;
      *(u32x4*)&Ks4[r * 32 + ((4 * s4 + 16) ^ sw)] = v1;
    }
    // ---- stage V transposed: Vt[d][k], words pack (k even, k odd) ----
    {
      const int k2 = 2 * (t & 31), d0 = 8 * (t >> 5);
      const unsigned short* vsrc =
          qkv + (size_t)(b * T_SEQ + kt * 64 + k2) * QKV_LD + 2048 + h * 64 + d0;
      union { u32x4 v; unsigned short us[8]; } va, vb;
      va.v = *(const u32x4*)(vsrc);
      vb.v = *(const u32x4*)(vsrc + QKV_LD);
#pragma unroll
      for (int j = 0; j < 8; ++j) {
        uint32_t pw = (uint32_t)va.us[j] | ((uint32_t)vb.us[j] << 16);
        Vt4[(d0 + j) * 32 + ((t & 31) ^ ((j & 7) << 2))] = pw;
      }
    }
    __syncthreads();

    // ---- QK^T + sigmoid + threefry sample, per 16-col chunk ----
    const int kt64 = kt * 64;
#pragma unroll
    for (int c = 0; c < 4; ++c) {
      const uint32_t* krow = &Ks4[(16 * c + lr) * 32];
      bf16x8 bk0 = *(const bf16x8*)&krow[(4 * g) ^ swzr];
      bf16x8 bk1 = *(const bf16x8*)&krow[(4 * g + 16) ^ swzr];
      f32x4 s = __builtin_amdgcn_mfma_f32_16x16x32_bf16(aq0, bk0, (f32x4){0.f, 0.f, 0.f, 0.f}, 0, 0, 0);
      s = __builtin_amdgcn_mfma_f32_16x16x32_bf16(aq1, bk1, s, 0, 0, 0);

      const int kg = kt64 + 16 * c + lr;
#pragma unroll
      for (int r = 0; r < 4; ++r) {
        const int qg = qt64 + 16 * w + 4 * g + r;
        float samp = 0.f;
        if (kg <= qg) {
          float e = __expf(-0.125f * s[r]);  // p = 1/(1+e)
          uint32_t idx = ((uint32_t)bh << 20) | ((uint32_t)qg << 10) | (uint32_t)kg;
          uint32_t r0, r1;
          threefry2x32(dk0, dk1, 0u, idx, r0, r1);
          float u = __uint_as_float(0x3F800000u | ((r0 ^ r1) >> 9)) - 1.0f;
          samp = (u * (1.0f + e) < 1.0f) ? 1.0f : 0.0f;
        }
        rs[r] += samp;
        St[(16 * w + 4 * g + r) * 68 + 16 * c + lr] = samp;
      }
    }
    // St rows [16w,16w+16) are wave-private: same-wave LDS dep, no barrier.

    // ---- Y += P @ V ----
#pragma unroll
    for (int ks = 0; ks < 2; ++ks) {
      const float* prow = &St[(16 * w + lr) * 68 + 8 * g + 32 * ks];
      f32x4 p0 = *(const f32x4*)(prow);
      f32x4 p1 = *(const f32x4*)(prow + 4);
      union { uint32_t u[4]; bf16x8 v; } pa;
      pa.u[0] = (__float_as_uint(p0.y) & 0xFFFF0000u) | (__float_as_uint(p0.x) >> 16);
      pa.u[1] = (__float_as_uint(p0.w) & 0xFFFF0000u) | (__float_as_uint(p0.z) >> 16);
      pa.u[2] = (__float_as_uint(p1.y) & 0xFFFF0000u) | (__float_as_uint(p1.x) >> 16);
      pa.u[3] = (__float_as_uint(p1.w) & 0xFFFF0000u) | (__float_as_uint(p1.z) >> 16);
#pragma unroll
      for (int c = 0; c < 4; ++c) {
        bf16x8 vb = *(const bf16x8*)&Vt4[(16 * c + lr) * 32 + ((4 * g + 16 * ks) ^ swzr)];
        yacc[c] = __builtin_amdgcn_mfma_f32_16x16x32_bf16(pa.v, vb, yacc[c], 0, 0, 0);
      }
    }
  }

  // ---- epilogue: yatt (bf16) + att_sum ----
  const size_t yb = (size_t)(b * T_SEQ + qt64 + 16 * w) * 1024 + h * 64;
#pragma unroll
  for (int c = 0; c < 4; ++c)
#pragma unroll
    for (int r = 0; r < 4; ++r)
      yatt[yb + (size_t)(4 * g + r) * 1024 + 16 * c + lr] = f2bf(yacc[c][r]);

#pragma unroll
  for (int r = 0; r < 4; ++r) {
    rs[r] += __shfl_xor(rs[r], 1);
    rs[r] += __shfl_xor(rs[r], 2);
    rs[r] += __shfl_xor(rs[r], 4);
    rs[r] += __shfl_xor(rs[r], 8);
  }
  if (lr == 0) {
#pragma unroll
    for (int r = 0; r < 4; ++r)
      att_sum[(size_t)bh * T_SEQ + qt64 + 16 * w + 4 * g + r] = rs[r];
  }
}

// att_var is exactly zero (samples are 0/1 => s*(1-s) == 0)
__global__ void zero_f4(float4* __restrict__ p) {
  p[(size_t)blockIdx.x * 256 + threadIdx.x] = make_float4(0.f, 0.f, 0.f, 0.f);
}

extern "C" void kernel_launch(void* const* d_in, const int* in_sizes, int n_in,
                              void* d_out, int out_size, void* d_ws, size_t ws_size,
                              hipStream_t stream) {
  (void)in_sizes; (void)n_in; (void)out_size; (void)ws_size;
  const float* x      = (const float*)d_in[0];  // [4,1024,1024]
  const float* w_attn = (const float*)d_in[1];  // [3072,1024]
  const float* w_proj = (const float*)d_in[2];  // [1024,1024]

  float* y_out      = (float*)d_out;                    // [4,1024,1024] f32
  float* attsum_out = y_out + (size_t)4 * 1024 * 1024;  // [4,16,1024]
  float* attvar_out = attsum_out + (size_t)4 * 16 * 1024;

  unsigned short* ws  = (unsigned short*)d_ws;
  unsigned short* x_bf   = ws;                            // 4M elems
  unsigned short* wa_bf  = x_bf + (size_t)4 * 1024 * 1024;   // 3M
  unsigned short* wp_bf  = wa_bf + (size_t)3 * 1024 * 1024;  // 1M
  unsigned short* qkv_bf = wp_bf + (size_t)1024 * 1024;      // 12M
  unsigned short* yatt_bf = qkv_bf + (size_t)4096 * 3072;    // 4M

  dim3 blk(256);
  cvt_bf16<<<dim3(4096), blk, 0, stream>>>((const float4*)x, (uint2*)x_bf);
  cvt_bf16<<<dim3(3072), blk, 0, stream>>>((const float4*)w_attn, (uint2*)wa_bf);
  cvt_bf16<<<dim3(1024), blk, 0, stream>>>((const float4*)w_proj, (uint2*)wp_bf);

  gemm_bf16<1><<<dim3(32, 24), blk, 0, stream>>>(x_bf, wa_bf, (void*)qkv_bf, 4096, 3072, 1024);
  attn_mfma<<<dim3(64, 16), blk, 0, stream>>>(qkv_bf, yatt_bf, attsum_out);
  gemm_bf16<0><<<dim3(32, 8), blk, 0, stream>>>(yatt_bf, wp_bf, (void*)y_out, 4096, 1024, 1024);
  zero_f4<<<dim3(64), blk, 0, stream>>>((float4*)attvar_out);
}

// Round 4
// 168.311 us; speedup vs baseline: 6.8602x; 1.0059x over previous
//
#include <hip/hip_runtime.h>
#include <stdint.h>

// ---------------------------------------------------------------------------
// B=4, T=1024, C=1024, H=16, hs=64.
// y = samples @ V (straight-through => forward output IS the Bernoulli sample),
// att_sum = per-row sample count, att_var == 0 exactly.
// Samples reproduce JAX partitionable threefry bit-exactly:
//   bits[i] = o0 ^ o1 of threefry(fold_in(key(0),42), (0, i)).
// ---------------------------------------------------------------------------

#define T_SEQ 1024
#define QKV_LD 3072

typedef __attribute__((ext_vector_type(8))) short bf16x8;
typedef __attribute__((ext_vector_type(4))) float f32x4;
typedef __attribute__((ext_vector_type(4))) unsigned int u32x4;

typedef __attribute__((address_space(3))) uint32_t lds_u32;
typedef __attribute__((address_space(1))) const uint32_t g_u32;

#define ROTL(x, d) __builtin_amdgcn_alignbit((x), (x), 32 - (d))

__device__ __forceinline__ void threefry2x32(uint32_t k0, uint32_t k1,
                                             uint32_t x0, uint32_t x1,
                                             uint32_t &o0, uint32_t &o1) {
  uint32_t ks2 = k0 ^ k1 ^ 0x1BD11BDAu;
#define TF_R4(a, b, c, d)                                                      \
  x0 += x1; x1 = ROTL(x1, a); x1 ^= x0;                                        \
  x0 += x1; x1 = ROTL(x1, b); x1 ^= x0;                                        \
  x0 += x1; x1 = ROTL(x1, c); x1 ^= x0;                                        \
  x0 += x1; x1 = ROTL(x1, d); x1 ^= x0;
  x0 += k0; x1 += k1;
  TF_R4(13, 15, 26, 6)
  x0 += k1; x1 += ks2 + 1u;
  TF_R4(17, 29, 16, 24)
  x0 += ks2; x1 += k0 + 2u;
  TF_R4(13, 15, 26, 6)
  x0 += k0; x1 += k1 + 3u;
  TF_R4(17, 29, 16, 24)
  x0 += k1; x1 += ks2 + 4u;
  TF_R4(13, 15, 26, 6)
  x0 += ks2; x1 += k0 + 5u;
  o0 = x0; o1 = x1;
#undef TF_R4
}

__device__ __forceinline__ unsigned short f2bf(float f) {  // RNE
  uint32_t u = __float_as_uint(f);
  u += 0x7FFFu + ((u >> 16) & 1u);
  return (unsigned short)(u >> 16);
}

// ---------------------------------------------------------------------------
// Fused f32->bf16 conversion of x, w_attn, w_proj (outputs contiguous in ws).
// ---------------------------------------------------------------------------
#define N_X4  1048576   // 4M f32 / 4
#define N_WA4 786432    // 3M / 4
#define N_WP4 262144    // 1M / 4

__global__ __launch_bounds__(256) void cvt3_bf16(const float4* __restrict__ x,
                                                 const float4* __restrict__ wa,
                                                 const float4* __restrict__ wp,
                                                 uint2* __restrict__ out) {
  size_t i = (size_t)blockIdx.x * 256 + threadIdx.x;
  const float4* src;
  size_t off;
  if (i < N_X4) { src = x; off = i; }
  else if (i < N_X4 + N_WA4) { src = wa; off = i - N_X4; }
  else { src = wp; off = i - (N_X4 + N_WA4); }
  float4 v = src[off];
  uint2 o;
  o.x = (uint32_t)f2bf(v.x) | ((uint32_t)f2bf(v.y) << 16);
  o.y = (uint32_t)f2bf(v.z) | ((uint32_t)f2bf(v.w) << 16);
  out[i] = o;
}

// ---------------------------------------------------------------------------
// bf16 MFMA GEMM: C[M,N] = A[M,K] @ B[N,K]^T. 128x128 tile, BK=32, 4 waves.
// m97 structure: global_load_lds width-16 into LINEAR LDS [row][32 bf16].
// ---------------------------------------------------------------------------
template <int OUT_BF16>
__global__ __launch_bounds__(256) void gemm_bf16(const unsigned short* __restrict__ A,
                                                 const unsigned short* __restrict__ B,
                                                 void* __restrict__ Cout,
                                                 int M, int N, int K) {
  __shared__ unsigned short As[128 * 32];  // 8 KB, linear
  __shared__ unsigned short Bs[128 * 32];

  const int t = threadIdx.x;
  const int lane = t & 63, w = t >> 6;
  const int g = lane >> 4, lr = lane & 15;
  const int rw = w >> 1, cw = w & 1;
  const int bm = blockIdx.x * 128, bn = blockIdx.y * 128;

  // staging: wave w covers rows [32w,32w+32); lane l -> row 32w+(l>>2), 16B chunk l&3
  const unsigned short* Ag = A + (size_t)(bm + 32 * w + (lane >> 2)) * K + 8 * (lane & 3);
  const unsigned short* Bg = B + (size_t)(bn + 32 * w + (lane >> 2)) * K + 8 * (lane & 3);
  lds_u32* Al0 = (lds_u32*)&As[(32 * w) * 32];
  lds_u32* Al1 = (lds_u32*)&As[(32 * w + 16) * 32];
  lds_u32* Bl0 = (lds_u32*)&Bs[(32 * w) * 32];
  lds_u32* Bl1 = (lds_u32*)&Bs[(32 * w + 16) * 32];

  f32x4 acc[4][4];
#pragma unroll
  for (int i = 0; i < 4; ++i)
#pragma unroll
    for (int j = 0; j < 4; ++j) acc[i][j] = (f32x4){0.f, 0.f, 0.f, 0.f};

  for (int k0 = 0; k0 < K; k0 += 32) {
    __syncthreads();  // prev frag reads done
    __builtin_amdgcn_global_load_lds((g_u32*)(const void*)(Ag + k0), Al0, 16, 0, 0);
    __builtin_amdgcn_global_load_lds((g_u32*)(const void*)(Ag + k0 + (size_t)16 * K), Al1, 16, 0, 0);
    __builtin_amdgcn_global_load_lds((g_u32*)(const void*)(Bg + k0), Bl0, 16, 0, 0);
    __builtin_amdgcn_global_load_lds((g_u32*)(const void*)(Bg + k0 + (size_t)16 * K), Bl1, 16, 0, 0);
    __syncthreads();  // drains vmcnt before barrier (compiler-inserted)

    bf16x8 af[4], bfr[4];
#pragma unroll
    for (int i = 0; i < 4; ++i)
      af[i] = *(const bf16x8*)&As[(64 * rw + 16 * i + lr) * 32 + 8 * g];
#pragma unroll
    for (int j = 0; j < 4; ++j)
      bfr[j] = *(const bf16x8*)&Bs[(64 * cw + 16 * j + lr) * 32 + 8 * g];
#pragma unroll
    for (int i = 0; i < 4; ++i)
#pragma unroll
      for (int j = 0; j < 4; ++j)
        acc[i][j] = __builtin_amdgcn_mfma_f32_16x16x32_bf16(af[i], bfr[j], acc[i][j], 0, 0, 0);
  }

#pragma unroll
  for (int i = 0; i < 4; ++i)
#pragma unroll
    for (int j = 0; j < 4; ++j)
#pragma unroll
      for (int r = 0; r < 4; ++r) {
        const size_t row = bm + 64 * rw + 16 * i + 4 * g + r;
        const size_t col = bn + 64 * cw + 16 * j + lr;
        if (OUT_BF16)
          ((unsigned short*)Cout)[row * N + col] = f2bf(acc[i][j][r]);
        else
          ((float*)Cout)[row * N + col] = acc[i][j][r];
      }
}

// ---------------------------------------------------------------------------
// Fused MFMA attention + exact threefry Bernoulli sampling.
// Block = (bh, diagonal pair): processes q-tiles (15-p) then (p) sequentially
// -> constant 17 k-steps per block, grid 512 = 2 blocks/CU, no tail.
// LDS: Ks/Vt bf16 tiles + QSt overlay (Q prologue tile / f32 sample buffer).
// ---------------------------------------------------------------------------
__global__ __launch_bounds__(256) void attn_mfma(const unsigned short* __restrict__ qkv,
                                                 unsigned short* __restrict__ yatt,
                                                 float* __restrict__ att_sum,
                                                 float* __restrict__ att_var) {
  __shared__ uint32_t Ks4[64 * 32];   // 8 KB
  __shared__ uint32_t Vt4[64 * 32];   // 8 KB
  __shared__ uint32_t QSt[64 * 72];   // 18 KB overlay: Q tile, then St (f32)

  const int t = threadIdx.x;
  const int lane = t & 63, w = t >> 6;
  const int g = lane >> 4, lr = lane & 15;
  // XCD-aware mapping: XCD x (= gid%8) sees bh in [8x,8x+8), all pairs.
  const int gid = blockIdx.x;  // 0..511
  const int bh = (gid & 7) * 8 + ((gid >> 3) & 7);
  const int pr = gid >> 6;     // 0..7
  const int b = bh >> 4, h = bh & 15;

  uint32_t dk0, dk1;  // fold_in(key(0), 42) -- uniform
  threefry2x32(0u, 0u, 0u, 42u, dk0, dk1);

  const int swzr = (lr & 7) << 2;

#pragma unroll 1
  for (int half = 0; half < 2; ++half) {
    const int qt = half == 0 ? (15 - pr) : pr;
    const int qt64 = qt * 64;

    __syncthreads();  // prior half's LDS reads complete
    // ---- stage Q tile into QSt (row stride 72 words, XOR swizzle) ----
    {
      const unsigned short* qbase = qkv + (size_t)(b * T_SEQ + qt64) * QKV_LD + h * 64;
      const int r = t >> 2, s4 = t & 3;
      const unsigned short* src = qbase + (size_t)r * QKV_LD + 8 * s4;
      u32x4 v0 = *(const u32x4*)(src);
      u32x4 v1 = *(const u32x4*)(src + 32);
      const int sw = (r & 7) << 2;
      *(u32x4*)&QSt[r * 72 + ((4 * s4) ^ sw)] = v0;
      *(u32x4*)&QSt[r * 72 + ((4 * s4 + 16) ^ sw)] = v1;
    }
    __syncthreads();

    bf16x8 aq0, aq1;  // Q A-frags (constant across k-tiles)
    {
      const uint32_t* qrow = &QSt[(16 * w + lr) * 72];
      aq0 = *(const bf16x8*)&qrow[(4 * g) ^ swzr];
      aq1 = *(const bf16x8*)&qrow[(4 * g + 16) ^ swzr];
    }

    f32x4 yacc[4];
#pragma unroll
    for (int c = 0; c < 4; ++c) yacc[c] = (f32x4){0.f, 0.f, 0.f, 0.f};
    float rs[4] = {0.f, 0.f, 0.f, 0.f};

    for (int kt = 0; kt <= qt; ++kt) {
      __syncthreads();  // prev Ks/Vt reads + all aq loads complete
      // ---- stage K tile ----
      const unsigned short* kb = qkv + (size_t)(b * T_SEQ + kt * 64) * QKV_LD + 1024 + h * 64;
      {
        const int r = t >> 2, s4 = t & 3;
        const unsigned short* src = kb + (size_t)r * QKV_LD + 8 * s4;
        u32x4 v0 = *(const u32x4*)(src);
        u32x4 v1 = *(const u32x4*)(src + 32);
        const int sw = (r & 7) << 2;
        *(u32x4*)&Ks4[r * 32 + ((4 * s4) ^ sw)] = v0;
        *(u32x4*)&Ks4[r * 32 + ((4 * s4 + 16) ^ sw)] = v1;
      }
      // ---- stage V transposed: Vt[d][k] ----
      {
        const int k2 = 2 * (t & 31), d0 = 8 * (t >> 5);
        const unsigned short* vsrc =
            qkv + (size_t)(b * T_SEQ + kt * 64 + k2) * QKV_LD + 2048 + h * 64 + d0;
        union { u32x4 v; unsigned short us[8]; } va, vb;
        va.v = *(const u32x4*)(vsrc);
        vb.v = *(const u32x4*)(vsrc + QKV_LD);
#pragma unroll
        for (int j = 0; j < 8; ++j) {
          uint32_t pw = (uint32_t)va.us[j] | ((uint32_t)vb.us[j] << 16);
          Vt4[(d0 + j) * 32 + ((t & 31) ^ ((j & 7) << 2))] = pw;
        }
      }
      __syncthreads();

      // ---- QK^T + sigmoid + threefry sample ----
      const int kt64 = kt * 64;
#pragma unroll
      for (int c = 0; c < 4; ++c) {
        const uint32_t* krow = &Ks4[(16 * c + lr) * 32];
        bf16x8 bk0 = *(const bf16x8*)&krow[(4 * g) ^ swzr];
        bf16x8 bk1 = *(const bf16x8*)&krow[(4 * g + 16) ^ swzr];
        f32x4 s = __builtin_amdgcn_mfma_f32_16x16x32_bf16(aq0, bk0, (f32x4){0.f, 0.f, 0.f, 0.f}, 0, 0, 0);
        s = __builtin_amdgcn_mfma_f32_16x16x32_bf16(aq1, bk1, s, 0, 0, 0);

        const int kg = kt64 + 16 * c + lr;
#pragma unroll
        for (int r = 0; r < 4; ++r) {
          const int qg = qt64 + 16 * w + 4 * g + r;
          float samp = 0.f;
          if (kg <= qg) {
            float e = __expf(-0.125f * s[r]);  // p = 1/(1+e)
            uint32_t idx = ((uint32_t)bh << 20) | ((uint32_t)qg << 10) | (uint32_t)kg;
            uint32_t r0, r1;
            threefry2x32(dk0, dk1, 0u, idx, r0, r1);
            float u = __uint_as_float(0x3F800000u | ((r0 ^ r1) >> 9)) - 1.0f;
            samp = (fmaf(u, e, u) < 1.0f) ? 1.0f : 0.0f;  // u(1+e) < 1
          }
          rs[r] += samp;
          const int row = 16 * w + 4 * g + r;
          ((float*)QSt)[row * 72 + ((16 * c + lr) ^ ((row & 7) << 2))] = samp;
        }
      }
      // St rows [16w,16w+16) are wave-private: same-wave LDS dep, no barrier.

      // ---- Y += P @ V ----
#pragma unroll
      for (int ks = 0; ks < 2; ++ks) {
        const float* srow = (const float*)&QSt[(16 * w + lr) * 72];
        f32x4 p0 = *(const f32x4*)&srow[(8 * g + 32 * ks) ^ swzr];
        f32x4 p1 = *(const f32x4*)&srow[(8 * g + 32 * ks + 4) ^ swzr];
        union { uint32_t u[4]; bf16x8 v; } pa;
        pa.u[0] = (__float_as_uint(p0.y) & 0xFFFF0000u) | (__float_as_uint(p0.x) >> 16);
        pa.u[1] = (__float_as_uint(p0.w) & 0xFFFF0000u) | (__float_as_uint(p0.z) >> 16);
        pa.u[2] = (__float_as_uint(p1.y) & 0xFFFF0000u) | (__float_as_uint(p1.x) >> 16);
        pa.u[3] = (__float_as_uint(p1.w) & 0xFFFF0000u) | (__float_as_uint(p1.z) >> 16);
#pragma unroll
        for (int c = 0; c < 4; ++c) {
          bf16x8 vb = *(const bf16x8*)&Vt4[(16 * c + lr) * 32 + ((4 * g + 16 * ks) ^ swzr)];
          yacc[c] = __builtin_amdgcn_mfma_f32_16x16x32_bf16(pa.v, vb, yacc[c], 0, 0, 0);
        }
      }
    }

    // ---- epilogue: yatt (bf16), att_sum, att_var zeros ----
    const size_t yb = (size_t)(b * T_SEQ + qt64 + 16 * w) * 1024 + h * 64;
#pragma unroll
    for (int c = 0; c < 4; ++c)
#pragma unroll
      for (int r = 0; r < 4; ++r)
        yatt[yb + (size_t)(4 * g + r) * 1024 + 16 * c + lr] = f2bf(yacc[c][r]);

#pragma unroll
    for (int r = 0; r < 4; ++r) {
      rs[r] += __shfl_xor(rs[r], 1);
      rs[r] += __shfl_xor(rs[r], 2);
      rs[r] += __shfl_xor(rs[r], 4);
      rs[r] += __shfl_xor(rs[r], 8);
    }
    if (lr == 0) {
#pragma unroll
      for (int r = 0; r < 4; ++r)
        att_sum[(size_t)bh * T_SEQ + qt64 + 16 * w + 4 * g + r] = rs[r];
    }
    if (t < 64) att_var[(size_t)bh * T_SEQ + qt64 + t] = 0.f;  // exact: s*(1-s)==0
  }
}

extern "C" void kernel_launch(void* const* d_in, const int* in_sizes, int n_in,
                              void* d_out, int out_size, void* d_ws, size_t ws_size,
                              hipStream_t stream) {
  (void)in_sizes; (void)n_in; (void)out_size; (void)ws_size;
  const float* x      = (const float*)d_in[0];  // [4,1024,1024]
  const float* w_attn = (const float*)d_in[1];  // [3072,1024]
  const float* w_proj = (const float*)d_in[2];  // [1024,1024]

  float* y_out      = (float*)d_out;                    // [4,1024,1024] f32
  float* attsum_out = y_out + (size_t)4 * 1024 * 1024;  // [4,16,1024]
  float* attvar_out = attsum_out + (size_t)4 * 16 * 1024;

  unsigned short* ws_us = (unsigned short*)d_ws;
  unsigned short* x_bf    = ws_us;                             // 4M elems
  unsigned short* wa_bf   = x_bf + (size_t)4 * 1024 * 1024;    // 3M
  unsigned short* wp_bf   = wa_bf + (size_t)3 * 1024 * 1024;   // 1M
  unsigned short* qkv_bf  = wp_bf + (size_t)1024 * 1024;       // 12M
  unsigned short* yatt_bf = qkv_bf + (size_t)4096 * 3072;      // 4M

  dim3 blk(256);
  cvt3_bf16<<<dim3(8192), blk, 0, stream>>>((const float4*)x, (const float4*)w_attn,
                                            (const float4*)w_proj, (uint2*)x_bf);
  gemm_bf16<1><<<dim3(32, 24), blk, 0, stream>>>(x_bf, wa_bf, (void*)qkv_bf, 4096, 3072, 1024);
  attn_mfma<<<dim3(512), blk, 0, stream>>>(qkv_bf, yatt_bf, attsum_out, attvar_out);
  gemm_bf16<0><<<dim3(32, 8), blk, 0, stream>>>(yatt_bf, wp_bf, (void*)y_out, 4096, 1024, 1024);
}